// Round 1
// baseline (109.573 us; speedup 1.0000x reference)
//
#include <hip/hip_runtime.h>
#include <math.h>

#define BS    32
#define T_    50
#define P_    3
#define TP    150     // T_ * P_
#define HEADS 4
#define NKP   88      // 44 keypoints * 2 coords

// One wave (64 lanes) per (b, i) row.
// Rows i < 147: softmax over <=9 unmasked columns (others underflow to exact 0 in ref).
// Rows i >= 147: fully masked row -> uniform softmax 1/TP, independent of attn.
__global__ __launch_bounds__(64) void smooth_rows(
    const int*   __restrict__ idx,
    const float* __restrict__ kp,     // (BS, TP, 88)
    const float* __restrict__ attn,   // (BS, H, TP, TP)
    float*       __restrict__ num_acc)
{
    int bi = blockIdx.x;
    int b  = bi / TP;
    int i  = bi - b * TP;
    int lane = threadIdx.x;

    int idx_i = idx[b * TP + i];
    if (idx_i == 0) return;   // whole-row contribution is exactly 0

    const float* kpb = kp + (size_t)b * TP * NKP;
    const float* kpi = kpb + i * NKP;

    __shared__ float s_kpi[NKP];
    __shared__ float s_lw[16];        // loss_kp[i,j] * idx[b,j] for each candidate j

    if (lane < NKP)      s_kpi[lane]      = kpi[lane];
    if (lane + 64 < NKP) s_kpi[lane + 64] = kpi[lane + 64];
    __syncthreads();

    if (i < (T_ - 1) * P_) {          // i < 147 : sparse-softmax path
        int f   = i / P_;
        int flo = f > 0 ? f - 1 : 0;
        int fhi = f < T_ - 2 ? f + 1 : T_ - 2;   // min(48, f+1)
        int jlo = flo * P_;
        int nj  = (fhi - flo + 1) * P_;          // 6 or 9

        float a0 = s_kpi[lane];                          // components 0..63
        float a1 = (lane < NKP - 64) ? s_kpi[lane + 64] : 0.f;  // 64..87

        for (int jj = 0; jj < nj; ++jj) {
            int j = jlo + jj;
            const float* kpj = kpb + j * NKP;
            float d = fabsf(kpj[lane] - a0);
            if (lane < NKP - 64) d += fabsf(kpj[lane + 64] - a1);
            #pragma unroll
            for (int off = 32; off; off >>= 1) d += __shfl_down(d, off);
            if (lane == 0) s_lw[jj] = d * (float)idx[b * TP + j];
        }
        __syncthreads();

        // lanes split into 4 groups of 16: group = head, lane-in-group = column
        int h  = lane >> 4;
        int jx = lane & 15;
        bool act = jx < nj;
        float a = act ? attn[(((size_t)b * HEADS + h) * TP + i) * TP + (jlo + jx)]
                      : -INFINITY;
        float m = a;
        #pragma unroll
        for (int off = 8; off; off >>= 1) m = fmaxf(m, __shfl_xor(m, off));
        float e = act ? expf(a - m) : 0.f;
        float w = act ? e * s_lw[jx] : 0.f;
        #pragma unroll
        for (int off = 8; off; off >>= 1) { e += __shfl_xor(e, off); w += __shfl_xor(w, off); }
        float ch = w / e;                 // per-head weighted mean
        float c0 = __shfl(ch, 0);
        float c1 = __shfl(ch, 16);
        float c2 = __shfl(ch, 32);
        float c3 = __shfl(ch, 48);
        if (lane == 0) atomicAdd(num_acc, c0 + c1 + c2 + c3);
    } else {                           // i >= 147 : uniform-softmax path
        float acc = 0.f;
        for (int j = lane; j < TP; j += 64) {
            if (idx[b * TP + j]) {
                const float* kpj = kpb + j * NKP;
                float s = 0.f;
                #pragma unroll
                for (int c = 0; c < NKP; ++c) s += fabsf(kpj[c] - s_kpi[c]);
                acc += s;
            }
        }
        #pragma unroll
        for (int off = 32; off; off >>= 1) acc += __shfl_down(acc, off);
        if (lane == 0) atomicAdd(num_acc, acc * ((float)HEADS / (float)TP));
    }
}

// den = 1 + H * sum_b (sum_i idx[b,i])^2 ; out = num / den
__global__ __launch_bounds__(256) void smooth_finalize(
    const int*   __restrict__ idx,
    const float* __restrict__ num_acc,
    float*       __restrict__ out)
{
    __shared__ int s_sb[BS];
    int tid = threadIdx.x;
    int b = tid >> 3;      // 8 threads per batch row
    int l = tid & 7;
    int s = 0;
    for (int k = l; k < TP; k += 8) s += idx[b * TP + k];
    #pragma unroll
    for (int off = 4; off; off >>= 1) s += __shfl_down(s, off, 8);
    if (l == 0) s_sb[b] = s;
    __syncthreads();
    if (tid == 0) {
        float tot = 0.f;
        for (int bb = 0; bb < BS; ++bb) {
            float v = (float)s_sb[bb];
            tot += v * v;
        }
        out[0] = num_acc[0] / (1.0f + (float)HEADS * tot);
    }
}

extern "C" void kernel_launch(void* const* d_in, const int* in_sizes, int n_in,
                              void* d_out, int out_size, void* d_ws, size_t ws_size,
                              hipStream_t stream)
{
    const int*   idx  = (const int*)  d_in[0];
    // d_in[1] = idx_mask (unused), d_in[2] = idx_kp (unused)
    const float* kp   = (const float*)d_in[3];
    const float* attn = (const float*)d_in[4];
    float* out     = (float*)d_out;
    float* num_acc = (float*)d_ws;

    hipMemsetAsync(num_acc, 0, sizeof(float), stream);
    smooth_rows<<<BS * TP, 64, 0, stream>>>(idx, kp, attn, num_acc);
    smooth_finalize<<<1, 256, 0, stream>>>(idx, num_acc, out);
}

// Round 2
// 84.822 us; speedup vs baseline: 1.2918x; 1.2918x over previous
//
#include <hip/hip_runtime.h>
#include <math.h>

#define BS    32
#define T_    50
#define P_    3
#define TP    150     // T_ * P_
#define HEADS 4
#define NKP   88      // 44 keypoints * 2 coords

// One wave (64 lanes) per (b, i) row. Each block writes its partial numerator
// contribution to partials[blockIdx] (no atomics -> no same-address serialization).
// Rows i < 147: softmax over <=9 unmasked columns (masked entries underflow to
// exact 0 in the fp32 reference). Rows i >= 147: fully masked row -> uniform
// softmax 1/TP, independent of attn.
__global__ __launch_bounds__(64) void smooth_rows(
    const int*   __restrict__ idx,
    const float* __restrict__ kp,     // (BS, TP, 88)
    const float* __restrict__ attn,   // (BS, H, TP, TP)
    float*       __restrict__ partials)
{
    int bi = blockIdx.x;
    int b  = bi / TP;
    int i  = bi - b * TP;
    int lane = threadIdx.x;

    int idx_i = idx[b * TP + i];
    if (idx_i == 0) {                 // exact-zero contribution; ws is poisoned -> must write
        if (lane == 0) partials[bi] = 0.f;
        return;
    }

    const float* kpb = kp + (size_t)b * TP * NKP;
    const float* kpi = kpb + i * NKP;

    __shared__ float s_kpi[NKP];
    __shared__ float s_lw[16];        // loss_kp[i,j] * idx[b,j] for each candidate j

    if (lane < NKP)      s_kpi[lane]      = kpi[lane];
    if (lane + 64 < NKP) s_kpi[lane + 64] = kpi[lane + 64];
    __syncthreads();

    if (i < (T_ - 1) * P_) {          // i < 147 : sparse-softmax path
        int f   = i / P_;
        int flo = f > 0 ? f - 1 : 0;
        int fhi = f < T_ - 2 ? f + 1 : T_ - 2;   // min(48, f+1)
        int jlo = flo * P_;
        int nj  = (fhi - flo + 1) * P_;          // 6 or 9

        float a0 = s_kpi[lane];                          // components 0..63
        float a1 = (lane < NKP - 64) ? s_kpi[lane + 64] : 0.f;  // 64..87

        for (int jj = 0; jj < nj; ++jj) {
            int j = jlo + jj;
            const float* kpj = kpb + j * NKP;
            float d = fabsf(kpj[lane] - a0);
            if (lane < NKP - 64) d += fabsf(kpj[lane + 64] - a1);
            #pragma unroll
            for (int off = 32; off; off >>= 1) d += __shfl_down(d, off);
            if (lane == 0) s_lw[jj] = d * (float)idx[b * TP + j];
        }
        __syncthreads();

        // lanes split into 4 groups of 16: group = head, lane-in-group = column
        int h  = lane >> 4;
        int jx = lane & 15;
        bool act = jx < nj;
        float a = act ? attn[(((size_t)b * HEADS + h) * TP + i) * TP + (jlo + jx)]
                      : -INFINITY;
        float m = a;
        #pragma unroll
        for (int off = 8; off; off >>= 1) m = fmaxf(m, __shfl_xor(m, off));
        float e = act ? expf(a - m) : 0.f;
        float w = act ? e * s_lw[jx] : 0.f;
        #pragma unroll
        for (int off = 8; off; off >>= 1) { e += __shfl_xor(e, off); w += __shfl_xor(w, off); }
        float ch = w / e;                 // per-head weighted mean
        float c0 = __shfl(ch, 0);
        float c1 = __shfl(ch, 16);
        float c2 = __shfl(ch, 32);
        float c3 = __shfl(ch, 48);
        if (lane == 0) partials[bi] = c0 + c1 + c2 + c3;
    } else {                           // i >= 147 : uniform-softmax path
        float acc = 0.f;
        for (int j = lane; j < TP; j += 64) {
            if (idx[b * TP + j]) {
                const float* kpj = kpb + j * NKP;
                float s = 0.f;
                #pragma unroll
                for (int c = 0; c < NKP; ++c) s += fabsf(kpj[c] - s_kpi[c]);
                acc += s;
            }
        }
        #pragma unroll
        for (int off = 32; off; off >>= 1) acc += __shfl_down(acc, off);
        if (lane == 0) partials[bi] = acc * ((float)HEADS / (float)TP);
    }
}

// Reduce 4800 partials; den = 1 + H * sum_b (sum_i idx[b,i])^2 ; out = num / den
__global__ __launch_bounds__(256) void smooth_reduce(
    const int*   __restrict__ idx,
    const float* __restrict__ partials,
    float*       __restrict__ out)
{
    int tid = threadIdx.x;

    // ---- numerator: sum of 4800 per-row partials ----
    float s = 0.f;
    for (int k = tid; k < BS * TP; k += 256) s += partials[k];
    #pragma unroll
    for (int off = 32; off; off >>= 1) s += __shfl_down(s, off);
    __shared__ float s_red[4];
    if ((tid & 63) == 0) s_red[tid >> 6] = s;

    // ---- denominator: per-batch idx sums (8 threads per batch) ----
    __shared__ int s_sb[BS];
    int b = tid >> 3;
    int l = tid & 7;
    int si = 0;
    for (int k = l; k < TP; k += 8) si += idx[b * TP + k];
    #pragma unroll
    for (int off = 4; off; off >>= 1) si += __shfl_down(si, off, 8);
    if (l == 0) s_sb[b] = si;
    __syncthreads();

    if (tid == 0) {
        float num = s_red[0] + s_red[1] + s_red[2] + s_red[3];
        float tot = 0.f;
        for (int bb = 0; bb < BS; ++bb) {
            float v = (float)s_sb[bb];
            tot += v * v;
        }
        out[0] = num / (1.0f + (float)HEADS * tot);
    }
}

extern "C" void kernel_launch(void* const* d_in, const int* in_sizes, int n_in,
                              void* d_out, int out_size, void* d_ws, size_t ws_size,
                              hipStream_t stream)
{
    const int*   idx  = (const int*)  d_in[0];
    // d_in[1] = idx_mask (unused), d_in[2] = idx_kp (unused)
    const float* kp   = (const float*)d_in[3];
    const float* attn = (const float*)d_in[4];
    float* out      = (float*)d_out;
    float* partials = (float*)d_ws;   // BS*TP floats

    smooth_rows<<<BS * TP, 64, 0, stream>>>(idx, kp, attn, partials);
    smooth_reduce<<<1, 256, 0, stream>>>(idx, partials, out);
}

// Round 3
// 83.216 us; speedup vs baseline: 1.3167x; 1.0193x over previous
//
#include <hip/hip_runtime.h>
#include <math.h>

#define BS    32
#define T_    50
#define P_    3
#define TP    150     // T_ * P_
#define HEADS 4
#define NKP   88      // 44 keypoints * 2 coords

// One wave (64 lanes) per (b, i) row. Each block writes its partial numerator
// contribution to partials[blockIdx] (no atomics).
// Rows i < 147: softmax over <=9 unmasked columns (masked entries underflow to
// exact 0 in the fp32 reference). Rows i >= 147: fully masked row -> uniform
// softmax 1/TP, independent of attn.
__global__ __launch_bounds__(64) void smooth_rows(
    const int*   __restrict__ idx,
    const float* __restrict__ kp,     // (BS, TP, 88)
    const float* __restrict__ attn,   // (BS, H, TP, TP)
    float*       __restrict__ partials)
{
    int bi = blockIdx.x;
    int b  = bi / TP;
    int i  = bi - b * TP;
    int lane = threadIdx.x;

    if (idx[b * TP + i] == 0) {       // exact-zero contribution; ws is poisoned -> must write
        if (lane == 0) partials[bi] = 0.f;
        return;
    }

    const float* kpb = kp + (size_t)b * TP * NKP;

    __shared__ __align__(16) float s_kpi[NKP];
    __shared__ float s_lw[9];         // loss_kp[i, jlo+jj] for each candidate column

    if (lane < NKP / 2)               // float2-vectorized stage of row i
        ((float2*)s_kpi)[lane] = ((const float2*)(kpb + i * NKP))[lane];
    __syncthreads();

    if (i < (T_ - 1) * P_) {          // i < 147 : sparse-softmax path
        int f   = i / P_;
        int flo = f > 0 ? f - 1 : 0;
        int fhi = f < T_ - 2 ? f + 1 : T_ - 2;
        int jlo = flo * P_;
        int nj  = (fhi - flo + 1) * P_;          // 6 or 9

        float a0 = s_kpi[lane];                          // components 0..63
        float a1 = (lane < NKP - 64) ? s_kpi[lane + 64] : 0.f;  // 64..87

        // fixed-trip unroll: all 18 global loads issue up front, reduce chains pipeline
        float d[9];
        #pragma unroll
        for (int jj = 0; jj < 9; ++jj) {
            int j = jlo + (jj < nj ? jj : 0);    // clamp keeps loads in-bounds; unused later
            const float* kpj = kpb + j * NKP;
            float t = fabsf(kpj[lane] - a0);
            if (lane < NKP - 64) t += fabsf(kpj[lane + 64] - a1);
            d[jj] = t;
        }
        #pragma unroll
        for (int jj = 0; jj < 9; ++jj) {
            #pragma unroll
            for (int off = 32; off; off >>= 1) d[jj] += __shfl_down(d[jj], off);
        }
        if (lane == 0) {
            #pragma unroll
            for (int jj = 0; jj < 9; ++jj) s_lw[jj] = d[jj];
        }
        __syncthreads();

        // lanes split into 4 groups of 16: group = head, lane-in-group = column
        int h  = lane >> 4;
        int jx = lane & 15;
        bool act = jx < nj;
        int  j  = jlo + (act ? jx : 0);
        float idxj = act ? (float)idx[b * TP + j] : 0.f;   // parallel, not lane0-serialized
        float a = act ? attn[(((size_t)b * HEADS + h) * TP + i) * TP + j]
                      : -INFINITY;
        float m = a;
        #pragma unroll
        for (int off = 8; off; off >>= 1) m = fmaxf(m, __shfl_xor(m, off));
        float e = act ? expf(a - m) : 0.f;
        float w = act ? e * s_lw[jx] * idxj : 0.f;   // idxj in {0,1}: exact
        #pragma unroll
        for (int off = 8; off; off >>= 1) { e += __shfl_xor(e, off); w += __shfl_xor(w, off); }
        float ch = w / e;                 // per-head weighted mean
        float c0 = __shfl(ch, 0);
        float c1 = __shfl(ch, 16);
        float c2 = __shfl(ch, 32);
        float c3 = __shfl(ch, 48);
        if (lane == 0) partials[bi] = c0 + c1 + c2 + c3;
    } else {                           // i >= 147 : uniform-softmax path
        float acc = 0.f;
        for (int j = lane; j < TP; j += 64) {
            if (idx[b * TP + j]) {
                const float4* kpj4 = (const float4*)(kpb + j * NKP);  // 88*4 B rows: 16B-aligned
                const float4* kpi4 = (const float4*)s_kpi;
                float s = 0.f;
                #pragma unroll
                for (int c = 0; c < NKP / 4; ++c) {
                    float4 q = kpj4[c];
                    float4 p = kpi4[c];
                    s += fabsf(q.x - p.x) + fabsf(q.y - p.y)
                       + fabsf(q.z - p.z) + fabsf(q.w - p.w);
                }
                acc += s;
            }
        }
        #pragma unroll
        for (int off = 32; off; off >>= 1) acc += __shfl_down(acc, off);
        if (lane == 0) partials[bi] = acc * ((float)HEADS / (float)TP);
    }
}

// Reduce 4800 partials; den = 1 + H * sum_b (sum_i idx[b,i])^2 ; out = num / den
__global__ __launch_bounds__(256) void smooth_reduce(
    const int*   __restrict__ idx,
    const float* __restrict__ partials,
    float*       __restrict__ out)
{
    int tid = threadIdx.x;

    // ---- numerator: sum of 4800 per-row partials ----
    float s = 0.f;
    for (int k = tid; k < BS * TP; k += 256) s += partials[k];
    #pragma unroll
    for (int off = 32; off; off >>= 1) s += __shfl_down(s, off);
    __shared__ float s_red[4];
    if ((tid & 63) == 0) s_red[tid >> 6] = s;

    // ---- denominator: per-batch idx sums (8 threads per batch) ----
    __shared__ int s_sb[BS];
    int b = tid >> 3;
    int l = tid & 7;
    int si = 0;
    for (int k = l; k < TP; k += 8) si += idx[b * TP + k];
    #pragma unroll
    for (int off = 4; off; off >>= 1) si += __shfl_down(si, off, 8);
    if (l == 0) s_sb[b] = si;
    __syncthreads();

    if (tid == 0) {
        float num = s_red[0] + s_red[1] + s_red[2] + s_red[3];
        float tot = 0.f;
        for (int bb = 0; bb < BS; ++bb) {
            float v = (float)s_sb[bb];
            tot += v * v;
        }
        out[0] = num / (1.0f + (float)HEADS * tot);
    }
}

extern "C" void kernel_launch(void* const* d_in, const int* in_sizes, int n_in,
                              void* d_out, int out_size, void* d_ws, size_t ws_size,
                              hipStream_t stream)
{
    const int*   idx  = (const int*)  d_in[0];
    // d_in[1] = idx_mask (unused), d_in[2] = idx_kp (unused)
    const float* kp   = (const float*)d_in[3];
    const float* attn = (const float*)d_in[4];
    float* out      = (float*)d_out;
    float* partials = (float*)d_ws;   // BS*TP floats

    smooth_rows<<<BS * TP, 64, 0, stream>>>(idx, kp, attn, partials);
    smooth_reduce<<<1, 256, 0, stream>>>(idx, partials, out);
}